// Round 8
// baseline (331.664 us; speedup 1.0000x reference)
//
#include <hip/hip_runtime.h>
#include <math.h>

#define NN 100000
#define NE 800000
#define D 128

typedef __attribute__((ext_vector_type(8))) short bf16x8;
typedef __attribute__((ext_vector_type(8))) unsigned short u16x8;
typedef __attribute__((ext_vector_type(4))) float f32x4;

// ---- workspace layout (bytes) ----
constexpr size_t OFF_RS  = 0;                         // int[NN+1]
constexpr size_t OFF_CNT = 512 * 1024;                // int[NN] histogram
constexpr size_t OFF_CUR = 1024 * 1024;               // int[NN] cursor -> row_end
constexpr size_t OFF_BS  = 1536 * 1024;               // int[512] block sums
constexpr size_t OFF_WB  = 1552 * 1024;               // bf16 weights (98304 elems)
constexpr size_t OFF_SRC = 2 * 1024 * 1024;           // int[NE]
constexpr size_t OFF_EID = 6 * 1024 * 1024;           // int[NE]
constexpr size_t OFF_B0  = 10 * 1024 * 1024;          // bf16[100096*128] xb -> Vb
constexpr size_t OFF_B2  = OFF_B0 + 26 * 1024 * 1024; // h1b
constexpr size_t OFF_B3  = OFF_B2 + 26 * 1024 * 1024; // Ub

__device__ __forceinline__ unsigned short f2b(float f) {
    unsigned u = __builtin_bit_cast(unsigned, f);
    return (unsigned short)((u + 0x7FFFu + ((u >> 16) & 1u)) >> 16);
}
__device__ __forceinline__ float b2f(unsigned short h) {
    unsigned u = ((unsigned)h) << 16;
    return __builtin_bit_cast(float, u);
}

// ------------- fused prep: x->bf16 | weights->bf16 | degree histogram -------
// (pure per-element map + order-independent integer atomics: replay-safe)
__global__ __launch_bounds__(256) void k_prep(const float* __restrict__ x,
                                              unsigned short* __restrict__ xb,
                                              const float* __restrict__ W1l,
                                              const float* __restrict__ W1r,
                                              const float* __restrict__ W2l,
                                              const float* __restrict__ W2r,
                                              const float* __restrict__ Wm1,
                                              unsigned short* __restrict__ wb,
                                              const int* __restrict__ dst,
                                              int* __restrict__ cnt) {
    int bid = blockIdx.x, tid = threadIdx.x;
    if (bid < 12500) {                       // x conversion, float4 granules
        int i = bid * 256 + tid;             // 12500*256 = 3,200,000 = NN*D/4 exactly
        float4 v = *(const float4*)&x[(size_t)i * 4];
        ushort4 o;
        o.x = f2b(v.x); o.y = f2b(v.y); o.z = f2b(v.z); o.w = f2b(v.w);
        *(ushort4*)&xb[(size_t)i * 4] = o;
    } else if (bid < 12884) {                // weights: 98304 elems
        int i = (bid - 12500) * 256 + tid;
        float v;
        if (i < 16384) v = W1l[i];
        else if (i < 32768) v = W1r[i - 16384];
        else if (i < 49152) v = W2l[i - 32768];
        else if (i < 65536) v = W2r[i - 49152];
        else v = Wm1[i - 65536];
        wb[i] = f2b(v);
    } else {                                 // degree histogram: 800000 edges
        int e = (bid - 12884) * 256 + tid;
        atomicAdd(&cnt[dst[e]], 1);
    }
}

// ---------------- CSR scan chain ----------------
__global__ __launch_bounds__(256) void k_scan1(const int* __restrict__ cnt,
                                               int* __restrict__ bsum) {
    int i = blockIdx.x * 256 + threadIdx.x;
    int v = (i < NN) ? cnt[i] : 0;
    #pragma unroll
    for (int o = 1; o < 64; o <<= 1) v += __shfl_xor(v, o);
    __shared__ int wsum[4];
    if ((threadIdx.x & 63) == 0) wsum[threadIdx.x >> 6] = v;
    __syncthreads();
    if (threadIdx.x == 0) bsum[blockIdx.x] = wsum[0] + wsum[1] + wsum[2] + wsum[3];
}

__global__ __launch_bounds__(512) void k_scan2(int* __restrict__ bsum, int nb) {
    __shared__ int s[512];
    int t = threadIdx.x;
    int v = (t < nb) ? bsum[t] : 0;
    s[t] = v;
    __syncthreads();
    for (int o = 1; o < 512; o <<= 1) {
        int u = (t >= o) ? s[t - o] : 0;
        __syncthreads();
        s[t] += u;
        __syncthreads();
    }
    if (t < nb) bsum[t] = s[t] - v;   // exclusive
}

__global__ __launch_bounds__(256) void k_scan3(const int* __restrict__ cnt,
                                               const int* __restrict__ bsum,
                                               int* __restrict__ rs,
                                               int* __restrict__ cur) {
    __shared__ int s[256];
    int t = threadIdx.x;
    int i = blockIdx.x * 256 + t;
    int v = (i < NN) ? cnt[i] : 0;
    s[t] = v;
    __syncthreads();
    for (int o = 1; o < 256; o <<= 1) {
        int u = (t >= o) ? s[t - o] : 0;
        __syncthreads();
        s[t] += u;
        __syncthreads();
    }
    int ex = s[t] - v + bsum[blockIdx.x];
    if (i < NN) { rs[i] = ex; cur[i] = ex; }
    if (i == NN - 1) rs[NN] = ex + v;
}

__global__ __launch_bounds__(256) void k_scatter_idx(const int* __restrict__ src,
                                                     const int* __restrict__ dst,
                                                     int* __restrict__ cur,
                                                     int* __restrict__ srcs,
                                                     int* __restrict__ eids) {
    int e = blockIdx.x * 256 + threadIdx.x;
    if (e < NE) {
        int pos = atomicAdd(&cur[dst[e]], 1);
        srcs[pos] = src[e];
        eids[pos] = e;
    }
}

// ---- gather-mean for 32 nodes into LDS tile [32][136] (bf16) --------------
// 16 lanes/node (round-6 proven mapping), inner loop 8-deep unrolled:
// 8 independent feature-row loads in flight per round.
__device__ __forceinline__ void gather_mean(const unsigned short* __restrict__ feat,
                                            const int* __restrict__ rs,
                                            const int* __restrict__ re,
                                            const int* __restrict__ srcs,
                                            int n0, unsigned short* agt) {
    const int tid = threadIdx.x;
    const int g = tid >> 4, q = tid & 15;
    #pragma unroll
    for (int half = 0; half < 2; ++half) {
        int n = n0 + half * 16 + g;
        int b = rs[n], e = re[n];
        float a0[8] = {}, a1[8] = {}, a2[8] = {}, a3[8] = {};
        int j = b;
        for (; j + 7 < e; j += 8) {
            int s0 = srcs[j],     s1 = srcs[j + 1], s2 = srcs[j + 2], s3 = srcs[j + 3];
            int s4 = srcs[j + 4], s5 = srcs[j + 5], s6 = srcs[j + 6], s7 = srcs[j + 7];
            u16x8 v0 = *(const u16x8*)&feat[(size_t)s0 * D + q * 8];
            u16x8 v1 = *(const u16x8*)&feat[(size_t)s1 * D + q * 8];
            u16x8 v2 = *(const u16x8*)&feat[(size_t)s2 * D + q * 8];
            u16x8 v3 = *(const u16x8*)&feat[(size_t)s3 * D + q * 8];
            u16x8 v4 = *(const u16x8*)&feat[(size_t)s4 * D + q * 8];
            u16x8 v5 = *(const u16x8*)&feat[(size_t)s5 * D + q * 8];
            u16x8 v6 = *(const u16x8*)&feat[(size_t)s6 * D + q * 8];
            u16x8 v7 = *(const u16x8*)&feat[(size_t)s7 * D + q * 8];
            #pragma unroll
            for (int i = 0; i < 8; ++i) a0[i] += b2f(v0[i]) + b2f(v4[i]);
            #pragma unroll
            for (int i = 0; i < 8; ++i) a1[i] += b2f(v1[i]) + b2f(v5[i]);
            #pragma unroll
            for (int i = 0; i < 8; ++i) a2[i] += b2f(v2[i]) + b2f(v6[i]);
            #pragma unroll
            for (int i = 0; i < 8; ++i) a3[i] += b2f(v3[i]) + b2f(v7[i]);
        }
        for (; j + 3 < e; j += 4) {
            int s0 = srcs[j], s1 = srcs[j + 1], s2 = srcs[j + 2], s3 = srcs[j + 3];
            u16x8 v0 = *(const u16x8*)&feat[(size_t)s0 * D + q * 8];
            u16x8 v1 = *(const u16x8*)&feat[(size_t)s1 * D + q * 8];
            u16x8 v2 = *(const u16x8*)&feat[(size_t)s2 * D + q * 8];
            u16x8 v3 = *(const u16x8*)&feat[(size_t)s3 * D + q * 8];
            #pragma unroll
            for (int i = 0; i < 8; ++i) a0[i] += b2f(v0[i]);
            #pragma unroll
            for (int i = 0; i < 8; ++i) a1[i] += b2f(v1[i]);
            #pragma unroll
            for (int i = 0; i < 8; ++i) a2[i] += b2f(v2[i]);
            #pragma unroll
            for (int i = 0; i < 8; ++i) a3[i] += b2f(v3[i]);
        }
        for (; j < e; ++j) {
            int s0 = srcs[j];
            u16x8 v0 = *(const u16x8*)&feat[(size_t)s0 * D + q * 8];
            #pragma unroll
            for (int i = 0; i < 8; ++i) a0[i] += b2f(v0[i]);
        }
        float inv = 1.0f / fmaxf((float)(e - b), 1.0f);
        u16x8 o;
        #pragma unroll
        for (int i = 0; i < 8; ++i) o[i] = f2b((a0[i] + a1[i] + a2[i] + a3[i]) * inv);
        *(u16x8*)&agt[(half * 16 + g) * 136 + q * 8] = o;
    }
}

// ---------------- fused agg + conv1: h1 = relu(mean@W1l^T + b + x@W1r^T) ----
__global__ __launch_bounds__(256) void k_aggconv1(const unsigned short* __restrict__ xb,
                                                  const int* __restrict__ rs,
                                                  const int* __restrict__ re,
                                                  const int* __restrict__ srcs,
                                                  const unsigned short* __restrict__ Wlb,
                                                  const unsigned short* __restrict__ Wrb,
                                                  const float* __restrict__ bias,
                                                  unsigned short* __restrict__ hout) {
    __shared__ unsigned short agt[32 * 136];
    __shared__ unsigned short sto[32 * 136];
    const int tid = threadIdx.x;
    const int n0 = blockIdx.x * 32;

    gather_mean(xb, rs, re, srcs, n0, agt);
    __syncthreads();

    const int wc = tid >> 6, l = tid & 63;
    const int lrow = l & 15, lk = (l >> 4) * 8;
    f32x4 acc[2][2] = {};
    #pragma unroll
    for (int p = 0; p < 2; ++p) {
        const unsigned short* W = p ? Wrb : Wlb;
        #pragma unroll
        for (int ks = 0; ks < 4; ++ks) {
            bf16x8 af0, af1;
            if (p == 0) {
                af0 = *(const bf16x8*)&agt[lrow * 136 + ks * 32 + lk];
                af1 = *(const bf16x8*)&agt[(16 + lrow) * 136 + ks * 32 + lk];
            } else {
                af0 = *(const bf16x8*)&xb[(size_t)(n0 + lrow) * D + ks * 32 + lk];
                af1 = *(const bf16x8*)&xb[(size_t)(n0 + 16 + lrow) * D + ks * 32 + lk];
            }
            #pragma unroll
            for (int nt = 0; nt < 2; ++nt) {
                bf16x8 bfr = *(const bf16x8*)&W[(size_t)(wc * 32 + nt * 16 + lrow) * D + ks * 32 + lk];
                acc[0][nt] = __builtin_amdgcn_mfma_f32_16x16x32_bf16(af0, bfr, acc[0][nt], 0, 0, 0);
                acc[1][nt] = __builtin_amdgcn_mfma_f32_16x16x32_bf16(af1, bfr, acc[1][nt], 0, 0, 0);
            }
        }
    }
    const int orow = (l >> 4) * 4, ocol = l & 15;
    #pragma unroll
    for (int nt = 0; nt < 2; ++nt) {
        float bb = bias[wc * 32 + nt * 16 + ocol];
        #pragma unroll
        for (int mt = 0; mt < 2; ++mt)
            #pragma unroll
            for (int j = 0; j < 4; ++j)
                sto[(mt * 16 + orow + j) * 136 + wc * 32 + nt * 16 + ocol] =
                    f2b(fmaxf(acc[mt][nt][j] + bb, 0.0f));
    }
    __syncthreads();
    #pragma unroll
    for (int it = 0; it < 2; ++it) {
        int r = it * 16 + (tid >> 4);
        int c = (tid & 15) * 8;
        u16x8 v = *(const u16x8*)&sto[r * 136 + c];
        *(u16x8*)&hout[(size_t)(n0 + r) * D + c] = v;
    }
}

// ------- fused agg + conv2 + U/V: h2 stays in LDS, U/V to global -------
__global__ __launch_bounds__(256) void k_aggconv2uv(const unsigned short* __restrict__ h1b,
                                                    const int* __restrict__ rs,
                                                    const int* __restrict__ re,
                                                    const int* __restrict__ srcs,
                                                    const unsigned short* __restrict__ Wlb,
                                                    const unsigned short* __restrict__ Wrb,
                                                    const float* __restrict__ bias,
                                                    const unsigned short* __restrict__ Wm1b,
                                                    const float* __restrict__ bm1,
                                                    unsigned short* __restrict__ Ub,
                                                    unsigned short* __restrict__ Vb) {
    __shared__ unsigned short agt[32 * 136];
    __shared__ unsigned short sto[32 * 136];
    const int tid = threadIdx.x;
    const int n0 = blockIdx.x * 32;

    gather_mean(h1b, rs, re, srcs, n0, agt);
    __syncthreads();

    const int wc = tid >> 6, l = tid & 63;
    const int lrow = l & 15, lk = (l >> 4) * 8;
    const int orow = (l >> 4) * 4, ocol = l & 15;

    {   // conv2 -> h2 tile in sto
        f32x4 acc[2][2] = {};
        #pragma unroll
        for (int p = 0; p < 2; ++p) {
            const unsigned short* W = p ? Wrb : Wlb;
            #pragma unroll
            for (int ks = 0; ks < 4; ++ks) {
                bf16x8 af0, af1;
                if (p == 0) {
                    af0 = *(const bf16x8*)&agt[lrow * 136 + ks * 32 + lk];
                    af1 = *(const bf16x8*)&agt[(16 + lrow) * 136 + ks * 32 + lk];
                } else {
                    af0 = *(const bf16x8*)&h1b[(size_t)(n0 + lrow) * D + ks * 32 + lk];
                    af1 = *(const bf16x8*)&h1b[(size_t)(n0 + 16 + lrow) * D + ks * 32 + lk];
                }
                #pragma unroll
                for (int nt = 0; nt < 2; ++nt) {
                    bf16x8 bfr = *(const bf16x8*)&W[(size_t)(wc * 32 + nt * 16 + lrow) * D + ks * 32 + lk];
                    acc[0][nt] = __builtin_amdgcn_mfma_f32_16x16x32_bf16(af0, bfr, acc[0][nt], 0, 0, 0);
                    acc[1][nt] = __builtin_amdgcn_mfma_f32_16x16x32_bf16(af1, bfr, acc[1][nt], 0, 0, 0);
                }
            }
        }
        #pragma unroll
        for (int nt = 0; nt < 2; ++nt) {
            float bb = bias[wc * 32 + nt * 16 + ocol];
            #pragma unroll
            for (int mt = 0; mt < 2; ++mt)
                #pragma unroll
                for (int j = 0; j < 4; ++j)
                    sto[(mt * 16 + orow + j) * 136 + wc * 32 + nt * 16 + ocol] =
                        f2b(fmaxf(acc[mt][nt][j] + bb, 0.0f));
        }
    }
    __syncthreads();   // (1) h2 complete; agt free from here

    bf16x8 af2[2][4];
    #pragma unroll
    for (int mt = 0; mt < 2; ++mt)
        #pragma unroll
        for (int ks = 0; ks < 4; ++ks)
            af2[mt][ks] = *(const bf16x8*)&sto[(mt * 16 + lrow) * 136 + ks * 32 + lk];

    f32x4 aU[2][2] = {}, aV[2][2] = {};
    #pragma unroll
    for (int ks = 0; ks < 4; ++ks)
        #pragma unroll
        for (int nt = 0; nt < 2; ++nt) {
            bf16x8 bu = *(const bf16x8*)&Wm1b[(size_t)(wc * 32 + nt * 16 + lrow) * 256 + ks * 32 + lk];
            bf16x8 bv = *(const bf16x8*)&Wm1b[(size_t)(wc * 32 + nt * 16 + lrow) * 256 + 128 + ks * 32 + lk];
            #pragma unroll
            for (int mt = 0; mt < 2; ++mt) {
                aU[mt][nt] = __builtin_amdgcn_mfma_f32_16x16x32_bf16(af2[mt][ks], bu, aU[mt][nt], 0, 0, 0);
                aV[mt][nt] = __builtin_amdgcn_mfma_f32_16x16x32_bf16(af2[mt][ks], bv, aV[mt][nt], 0, 0, 0);
            }
        }
    // stage U into agt (agt safe after sync(1))
    #pragma unroll
    for (int nt = 0; nt < 2; ++nt) {
        float bb = bm1[wc * 32 + nt * 16 + ocol];
        #pragma unroll
        for (int mt = 0; mt < 2; ++mt)
            #pragma unroll
            for (int j = 0; j < 4; ++j)
                agt[(mt * 16 + orow + j) * 136 + wc * 32 + nt * 16 + ocol] = f2b(aU[mt][nt][j] + bb);
    }
    __syncthreads();   // (2) all af2 reads done, U staged
    // store U; stage V into sto (overwrites h2, safe after sync(2))
    #pragma unroll
    for (int it = 0; it < 2; ++it) {
        int r = it * 16 + (tid >> 4);
        int c = (tid & 15) * 8;
        u16x8 v = *(const u16x8*)&agt[r * 136 + c];
        *(u16x8*)&Ub[(size_t)(n0 + r) * D + c] = v;
    }
    #pragma unroll
    for (int nt = 0; nt < 2; ++nt) {
        #pragma unroll
        for (int mt = 0; mt < 2; ++mt)
            #pragma unroll
            for (int j = 0; j < 4; ++j)
                sto[(mt * 16 + orow + j) * 136 + wc * 32 + nt * 16 + ocol] = f2b(aV[mt][nt][j]);
    }
    __syncthreads();   // (3)
    #pragma unroll
    for (int it = 0; it < 2; ++it) {
        int r = it * 16 + (tid >> 4);
        int c = (tid & 15) * 8;
        u16x8 v = *(const u16x8*)&sto[r * 136 + c];
        *(u16x8*)&Vb[(size_t)(n0 + r) * D + c] = v;
    }
}

// ---------------- edge finalize, dst-grouped (round-6 mapping), 8-unrolled --
__global__ __launch_bounds__(256) void k_edge2(const unsigned short* __restrict__ Ub,
                                               const unsigned short* __restrict__ Vb,
                                               const int* __restrict__ rs,
                                               const int* __restrict__ re,
                                               const int* __restrict__ srcs,
                                               const int* __restrict__ eids,
                                               const float* __restrict__ wm2,
                                               const float* __restrict__ bm2,
                                               float* __restrict__ out) {
    int t = blockIdx.x * 256 + threadIdx.x;
    int g = t >> 4, q = t & 15;
    if (g >= NN) return;
    int b = rs[g], e = re[g];
    if (b == e) return;
    u16x8 vv = *(const u16x8*)&Vb[(size_t)g * D + q * 8];
    float vf[8], wf[8];
    #pragma unroll
    for (int i = 0; i < 8; ++i) vf[i] = b2f(vv[i]);
    float4 w0 = *(const float4*)&wm2[q * 8];
    float4 w1 = *(const float4*)&wm2[q * 8 + 4];
    wf[0] = w0.x; wf[1] = w0.y; wf[2] = w0.z; wf[3] = w0.w;
    wf[4] = w1.x; wf[5] = w1.y; wf[6] = w1.z; wf[7] = w1.w;
    const float bb = bm2[0];

    int j = b;
    for (; j + 7 < e; j += 8) {
        u16x8 u0 = *(const u16x8*)&Ub[(size_t)srcs[j]     * D + q * 8];
        u16x8 u1 = *(const u16x8*)&Ub[(size_t)srcs[j + 1] * D + q * 8];
        u16x8 u2 = *(const u16x8*)&Ub[(size_t)srcs[j + 2] * D + q * 8];
        u16x8 u3 = *(const u16x8*)&Ub[(size_t)srcs[j + 3] * D + q * 8];
        u16x8 u4 = *(const u16x8*)&Ub[(size_t)srcs[j + 4] * D + q * 8];
        u16x8 u5 = *(const u16x8*)&Ub[(size_t)srcs[j + 5] * D + q * 8];
        u16x8 u6 = *(const u16x8*)&Ub[(size_t)srcs[j + 6] * D + q * 8];
        u16x8 u7 = *(const u16x8*)&Ub[(size_t)srcs[j + 7] * D + q * 8];
        float p0 = 0.f, p1 = 0.f, p2 = 0.f, p3 = 0.f;
        float p4 = 0.f, p5 = 0.f, p6 = 0.f, p7 = 0.f;
        #pragma unroll
        for (int i = 0; i < 8; ++i) {
            p0 += fmaxf(b2f(u0[i]) + vf[i], 0.0f) * wf[i];
            p1 += fmaxf(b2f(u1[i]) + vf[i], 0.0f) * wf[i];
            p2 += fmaxf(b2f(u2[i]) + vf[i], 0.0f) * wf[i];
            p3 += fmaxf(b2f(u3[i]) + vf[i], 0.0f) * wf[i];
            p4 += fmaxf(b2f(u4[i]) + vf[i], 0.0f) * wf[i];
            p5 += fmaxf(b2f(u5[i]) + vf[i], 0.0f) * wf[i];
            p6 += fmaxf(b2f(u6[i]) + vf[i], 0.0f) * wf[i];
            p7 += fmaxf(b2f(u7[i]) + vf[i], 0.0f) * wf[i];
        }
        #pragma unroll
        for (int off = 1; off < 16; off <<= 1) {
            p0 += __shfl_xor(p0, off); p1 += __shfl_xor(p1, off);
            p2 += __shfl_xor(p2, off); p3 += __shfl_xor(p3, off);
            p4 += __shfl_xor(p4, off); p5 += __shfl_xor(p5, off);
            p6 += __shfl_xor(p6, off); p7 += __shfl_xor(p7, off);
        }
        if (q == 0) {
            out[eids[j]]     = 1.0f / (1.0f + expf(-(p0 + bb)));
            out[eids[j + 1]] = 1.0f / (1.0f + expf(-(p1 + bb)));
            out[eids[j + 2]] = 1.0f / (1.0f + expf(-(p2 + bb)));
            out[eids[j + 3]] = 1.0f / (1.0f + expf(-(p3 + bb)));
            out[eids[j + 4]] = 1.0f / (1.0f + expf(-(p4 + bb)));
            out[eids[j + 5]] = 1.0f / (1.0f + expf(-(p5 + bb)));
            out[eids[j + 6]] = 1.0f / (1.0f + expf(-(p6 + bb)));
            out[eids[j + 7]] = 1.0f / (1.0f + expf(-(p7 + bb)));
        }
    }
    for (; j + 3 < e; j += 4) {
        u16x8 u0 = *(const u16x8*)&Ub[(size_t)srcs[j]     * D + q * 8];
        u16x8 u1 = *(const u16x8*)&Ub[(size_t)srcs[j + 1] * D + q * 8];
        u16x8 u2 = *(const u16x8*)&Ub[(size_t)srcs[j + 2] * D + q * 8];
        u16x8 u3 = *(const u16x8*)&Ub[(size_t)srcs[j + 3] * D + q * 8];
        float p0 = 0.f, p1 = 0.f, p2 = 0.f, p3 = 0.f;
        #pragma unroll
        for (int i = 0; i < 8; ++i) {
            p0 += fmaxf(b2f(u0[i]) + vf[i], 0.0f) * wf[i];
            p1 += fmaxf(b2f(u1[i]) + vf[i], 0.0f) * wf[i];
            p2 += fmaxf(b2f(u2[i]) + vf[i], 0.0f) * wf[i];
            p3 += fmaxf(b2f(u3[i]) + vf[i], 0.0f) * wf[i];
        }
        #pragma unroll
        for (int off = 1; off < 16; off <<= 1) {
            p0 += __shfl_xor(p0, off); p1 += __shfl_xor(p1, off);
            p2 += __shfl_xor(p2, off); p3 += __shfl_xor(p3, off);
        }
        if (q == 0) {
            out[eids[j]]     = 1.0f / (1.0f + expf(-(p0 + bb)));
            out[eids[j + 1]] = 1.0f / (1.0f + expf(-(p1 + bb)));
            out[eids[j + 2]] = 1.0f / (1.0f + expf(-(p2 + bb)));
            out[eids[j + 3]] = 1.0f / (1.0f + expf(-(p3 + bb)));
        }
    }
    for (; j < e; ++j) {
        u16x8 u0 = *(const u16x8*)&Ub[(size_t)srcs[j] * D + q * 8];
        float p0 = 0.f;
        #pragma unroll
        for (int i = 0; i < 8; ++i) p0 += fmaxf(b2f(u0[i]) + vf[i], 0.0f) * wf[i];
        #pragma unroll
        for (int off = 1; off < 16; off <<= 1) p0 += __shfl_xor(p0, off);
        if (q == 0) out[eids[j]] = 1.0f / (1.0f + expf(-(p0 + bb)));
    }
}

extern "C" void kernel_launch(void* const* d_in, const int* in_sizes, int n_in,
                              void* d_out, int out_size, void* d_ws, size_t ws_size,
                              hipStream_t stream) {
    const float* x   = (const float*)d_in[0];
    const int*   ei  = (const int*)d_in[1];
    const int*   src = ei;
    const int*   dst = ei + NE;
    const float* W1l = (const float*)d_in[2];
    const float* b1l = (const float*)d_in[3];
    const float* W1r = (const float*)d_in[4];
    const float* W2l = (const float*)d_in[5];
    const float* b2l = (const float*)d_in[6];
    const float* W2r = (const float*)d_in[7];
    const float* Wm1 = (const float*)d_in[8];
    const float* bm1 = (const float*)d_in[9];
    const float* Wm2 = (const float*)d_in[10];
    const float* bm2 = (const float*)d_in[11];
    float* out = (float*)d_out;

    char* ws = (char*)d_ws;
    int* rs   = (int*)(ws + OFF_RS);
    int* cnt  = (int*)(ws + OFF_CNT);
    int* cur  = (int*)(ws + OFF_CUR);    // row_end after scatter_idx
    int* bsum = (int*)(ws + OFF_BS);
    unsigned short* wb = (unsigned short*)(ws + OFF_WB);
    int* srcs = (int*)(ws + OFF_SRC);
    int* eids = (int*)(ws + OFF_EID);
    unsigned short* B0 = (unsigned short*)(ws + OFF_B0);  // xb, later Vb
    unsigned short* B2 = (unsigned short*)(ws + OFF_B2);  // h1b
    unsigned short* B3 = (unsigned short*)(ws + OFF_B3);  // Ub

    unsigned short* W1lb = wb;
    unsigned short* W1rb = wb + 16384;
    unsigned short* W2lb = wb + 32768;
    unsigned short* W2rb = wb + 49152;
    unsigned short* Wm1b = wb + 65536;

    const int NB = 391;  // ceil(NN/256)

    hipMemsetAsync(cnt, 0, NN * sizeof(int), stream);
    k_prep<<<12500 + 384 + 3125, 256, 0, stream>>>(x, B0, W1l, W1r, W2l, W2r, Wm1,
                                                   wb, dst, cnt);
    k_scan1<<<NB, 256, 0, stream>>>(cnt, bsum);
    k_scan2<<<1, 512, 0, stream>>>(bsum, NB);
    k_scan3<<<NB, 256, 0, stream>>>(cnt, bsum, rs, cur);
    k_scatter_idx<<<(NE + 255) / 256, 256, 0, stream>>>(src, dst, cur, srcs, eids);

    k_aggconv1<<<NN / 32, 256, 0, stream>>>(B0, rs, cur, srcs, W1lb, W1rb, b1l, B2);   // h1 -> B2
    k_aggconv2uv<<<NN / 32, 256, 0, stream>>>(B2, rs, cur, srcs, W2lb, W2rb, b2l,
                                              Wm1b, bm1, B3, B0);                      // U -> B3, V -> B0
    k_edge2<<<(NN * 16 + 255) / 256, 256, 0, stream>>>(B3, B0, rs, cur, srcs, eids,
                                                       Wm2, bm2, out);
}

// Round 9
// 288.373 us; speedup vs baseline: 1.1501x; 1.1501x over previous
//
#include <hip/hip_runtime.h>
#include <math.h>

#define NN 100000
#define NE 800000
#define D 128

typedef __attribute__((ext_vector_type(8))) short bf16x8;
typedef __attribute__((ext_vector_type(8))) unsigned short u16x8;
typedef __attribute__((ext_vector_type(4))) float f32x4;

// ---- workspace layout (bytes) ----
constexpr size_t OFF_RS  = 0;                         // int[NN+1]
constexpr size_t OFF_CNT = 512 * 1024;                // int[NN] histogram
constexpr size_t OFF_CUR = 1024 * 1024;               // int[NN] cursor -> row_end
constexpr size_t OFF_BS  = 1536 * 1024;               // int[512] block sums
constexpr size_t OFF_WB  = 1552 * 1024;               // bf16 weights (98304 elems)
constexpr size_t OFF_SRC = 2 * 1024 * 1024;           // int[NE]
constexpr size_t OFF_EID = 6 * 1024 * 1024;           // int[NE]
constexpr size_t OFF_B0  = 10 * 1024 * 1024;          // bf16[100096*128] xb -> Vb
constexpr size_t OFF_B2  = OFF_B0 + 26 * 1024 * 1024; // h1b
constexpr size_t OFF_B3  = OFF_B2 + 26 * 1024 * 1024; // Ub

__device__ __forceinline__ unsigned short f2b(float f) {
    unsigned u = __builtin_bit_cast(unsigned, f);
    return (unsigned short)((u + 0x7FFFu + ((u >> 16) & 1u)) >> 16);
}
__device__ __forceinline__ float b2f(unsigned short h) {
    unsigned u = ((unsigned)h) << 16;
    return __builtin_bit_cast(float, u);
}

// ------------- fused prep: x->bf16 | weights->bf16 | degree histogram -------
__global__ __launch_bounds__(256) void k_prep(const float* __restrict__ x,
                                              unsigned short* __restrict__ xb,
                                              const float* __restrict__ W1l,
                                              const float* __restrict__ W1r,
                                              const float* __restrict__ W2l,
                                              const float* __restrict__ W2r,
                                              const float* __restrict__ Wm1,
                                              unsigned short* __restrict__ wb,
                                              const int* __restrict__ dst,
                                              int* __restrict__ cnt) {
    int bid = blockIdx.x, tid = threadIdx.x;
    if (bid < 12500) {                       // x conversion, float4 granules
        int i = bid * 256 + tid;             // 12500*256 = 3,200,000 = NN*D/4 exactly
        float4 v = *(const float4*)&x[(size_t)i * 4];
        ushort4 o;
        o.x = f2b(v.x); o.y = f2b(v.y); o.z = f2b(v.z); o.w = f2b(v.w);
        *(ushort4*)&xb[(size_t)i * 4] = o;
    } else if (bid < 12884) {                // weights: 98304 elems
        int i = (bid - 12500) * 256 + tid;
        float v;
        if (i < 16384) v = W1l[i];
        else if (i < 32768) v = W1r[i - 16384];
        else if (i < 49152) v = W2l[i - 32768];
        else if (i < 65536) v = W2r[i - 49152];
        else v = Wm1[i - 65536];
        wb[i] = f2b(v);
    } else {                                 // degree histogram: 800000 edges
        int e = (bid - 12884) * 256 + tid;
        atomicAdd(&cnt[dst[e]], 1);
    }
}

// ---------------- CSR scan chain ----------------
__global__ __launch_bounds__(256) void k_scan1(const int* __restrict__ cnt,
                                               int* __restrict__ bsum) {
    int i = blockIdx.x * 256 + threadIdx.x;
    int v = (i < NN) ? cnt[i] : 0;
    #pragma unroll
    for (int o = 1; o < 64; o <<= 1) v += __shfl_xor(v, o);
    __shared__ int wsum[4];
    if ((threadIdx.x & 63) == 0) wsum[threadIdx.x >> 6] = v;
    __syncthreads();
    if (threadIdx.x == 0) bsum[blockIdx.x] = wsum[0] + wsum[1] + wsum[2] + wsum[3];
}

__global__ __launch_bounds__(512) void k_scan2(int* __restrict__ bsum, int nb) {
    __shared__ int s[512];
    int t = threadIdx.x;
    int v = (t < nb) ? bsum[t] : 0;
    s[t] = v;
    __syncthreads();
    for (int o = 1; o < 512; o <<= 1) {
        int u = (t >= o) ? s[t - o] : 0;
        __syncthreads();
        s[t] += u;
        __syncthreads();
    }
    if (t < nb) bsum[t] = s[t] - v;   // exclusive
}

__global__ __launch_bounds__(256) void k_scan3(const int* __restrict__ cnt,
                                               const int* __restrict__ bsum,
                                               int* __restrict__ rs,
                                               int* __restrict__ cur) {
    __shared__ int s[256];
    int t = threadIdx.x;
    int i = blockIdx.x * 256 + t;
    int v = (i < NN) ? cnt[i] : 0;
    s[t] = v;
    __syncthreads();
    for (int o = 1; o < 256; o <<= 1) {
        int u = (t >= o) ? s[t - o] : 0;
        __syncthreads();
        s[t] += u;
        __syncthreads();
    }
    int ex = s[t] - v + bsum[blockIdx.x];
    if (i < NN) { rs[i] = ex; cur[i] = ex; }
    if (i == NN - 1) rs[NN] = ex + v;
}

__global__ __launch_bounds__(256) void k_scatter_idx(const int* __restrict__ src,
                                                     const int* __restrict__ dst,
                                                     int* __restrict__ cur,
                                                     int* __restrict__ srcs,
                                                     int* __restrict__ eids) {
    int e = blockIdx.x * 256 + threadIdx.x;
    if (e < NE) {
        int pos = atomicAdd(&cur[dst[e]], 1);
        srcs[pos] = src[e];
        eids[pos] = e;
    }
}

// ---- gather-mean for 64 nodes into LDS tile [64][136] (bf16), 512 thr -----
// 16 lanes/node (proven mapping), 32 groups x 2 sequential nodes, 8-deep MLP.
__device__ __forceinline__ void gather_mean64(const unsigned short* __restrict__ feat,
                                              const int* __restrict__ rs,
                                              const int* __restrict__ re,
                                              const int* __restrict__ srcs,
                                              int n0, unsigned short* agt) {
    const int tid = threadIdx.x;
    const int g = tid >> 4, q = tid & 15;   // g in 0..31
    #pragma unroll
    for (int half = 0; half < 2; ++half) {
        int r = half * 32 + g;
        int n = n0 + r;
        if (n > NN - 1) n = NN - 1;          // tail clamp (NN%64==32)
        int b = rs[n], e = re[n];
        float a0[8] = {}, a1[8] = {}, a2[8] = {}, a3[8] = {};
        int j = b;
        for (; j + 7 < e; j += 8) {
            int s0 = srcs[j],     s1 = srcs[j + 1], s2 = srcs[j + 2], s3 = srcs[j + 3];
            int s4 = srcs[j + 4], s5 = srcs[j + 5], s6 = srcs[j + 6], s7 = srcs[j + 7];
            u16x8 v0 = *(const u16x8*)&feat[(size_t)s0 * D + q * 8];
            u16x8 v1 = *(const u16x8*)&feat[(size_t)s1 * D + q * 8];
            u16x8 v2 = *(const u16x8*)&feat[(size_t)s2 * D + q * 8];
            u16x8 v3 = *(const u16x8*)&feat[(size_t)s3 * D + q * 8];
            u16x8 v4 = *(const u16x8*)&feat[(size_t)s4 * D + q * 8];
            u16x8 v5 = *(const u16x8*)&feat[(size_t)s5 * D + q * 8];
            u16x8 v6 = *(const u16x8*)&feat[(size_t)s6 * D + q * 8];
            u16x8 v7 = *(const u16x8*)&feat[(size_t)s7 * D + q * 8];
            #pragma unroll
            for (int i = 0; i < 8; ++i) a0[i] += b2f(v0[i]) + b2f(v4[i]);
            #pragma unroll
            for (int i = 0; i < 8; ++i) a1[i] += b2f(v1[i]) + b2f(v5[i]);
            #pragma unroll
            for (int i = 0; i < 8; ++i) a2[i] += b2f(v2[i]) + b2f(v6[i]);
            #pragma unroll
            for (int i = 0; i < 8; ++i) a3[i] += b2f(v3[i]) + b2f(v7[i]);
        }
        for (; j + 3 < e; j += 4) {
            int s0 = srcs[j], s1 = srcs[j + 1], s2 = srcs[j + 2], s3 = srcs[j + 3];
            u16x8 v0 = *(const u16x8*)&feat[(size_t)s0 * D + q * 8];
            u16x8 v1 = *(const u16x8*)&feat[(size_t)s1 * D + q * 8];
            u16x8 v2 = *(const u16x8*)&feat[(size_t)s2 * D + q * 8];
            u16x8 v3 = *(const u16x8*)&feat[(size_t)s3 * D + q * 8];
            #pragma unroll
            for (int i = 0; i < 8; ++i) a0[i] += b2f(v0[i]);
            #pragma unroll
            for (int i = 0; i < 8; ++i) a1[i] += b2f(v1[i]);
            #pragma unroll
            for (int i = 0; i < 8; ++i) a2[i] += b2f(v2[i]);
            #pragma unroll
            for (int i = 0; i < 8; ++i) a3[i] += b2f(v3[i]);
        }
        for (; j < e; ++j) {
            int s0 = srcs[j];
            u16x8 v0 = *(const u16x8*)&feat[(size_t)s0 * D + q * 8];
            #pragma unroll
            for (int i = 0; i < 8; ++i) a0[i] += b2f(v0[i]);
        }
        float inv = 1.0f / fmaxf((float)(e - b), 1.0f);
        u16x8 o;
        #pragma unroll
        for (int i = 0; i < 8; ++i) o[i] = f2b((a0[i] + a1[i] + a2[i] + a3[i]) * inv);
        *(u16x8*)&agt[r * 136 + q * 8] = o;
    }
}

// stage 64 global rows -> LDS tile [64][136] (coalesced, clamped)
__device__ __forceinline__ void stage_tile(const unsigned short* __restrict__ src,
                                           int n0, unsigned short* t) {
    const int tid = threadIdx.x;
    #pragma unroll
    for (int it = 0; it < 2; ++it) {
        int idx = it * 512 + tid;
        int r = idx >> 4, c = (idx & 15) * 8;
        int gr = n0 + r;
        if (gr > NN - 1) gr = NN - 1;
        *(u16x8*)&t[r * 136 + c] = *(const u16x8*)&src[(size_t)gr * D + c];
    }
}

// store LDS tile [64][136] -> global (coalesced, guarded)
__device__ __forceinline__ void store_tile(const unsigned short* t,
                                           int n0, unsigned short* __restrict__ dstp) {
    const int tid = threadIdx.x;
    #pragma unroll
    for (int it = 0; it < 2; ++it) {
        int idx = it * 512 + tid;
        int r = idx >> 4, c = (idx & 15) * 8;
        int gr = n0 + r;
        if (gr < NN)
            *(u16x8*)&dstp[(size_t)gr * D + c] = *(const u16x8*)&t[r * 136 + c];
    }
}

// ---------------- fused agg + conv1: h1 = relu(mean@W1l^T + b + x@W1r^T) ----
// 512 thr = 8 waves; 64-row tile; wave owns 16 cols; all A-frags from LDS.
__global__ __launch_bounds__(512) void k_aggconv1(const unsigned short* __restrict__ xb,
                                                  const int* __restrict__ rs,
                                                  const int* __restrict__ re,
                                                  const int* __restrict__ srcs,
                                                  const unsigned short* __restrict__ Wlb,
                                                  const unsigned short* __restrict__ Wrb,
                                                  const float* __restrict__ bias,
                                                  unsigned short* __restrict__ hout) {
    __shared__ unsigned short agt[64 * 136];
    __shared__ unsigned short sto[64 * 136];
    const int tid = threadIdx.x;
    const int n0 = blockIdx.x * 64;

    stage_tile(xb, n0, sto);
    gather_mean64(xb, rs, re, srcs, n0, agt);
    __syncthreads();

    const int wv = tid >> 6, l = tid & 63;
    const int lrow = l & 15, lk = (l >> 4) * 8;
    f32x4 acc[4] = {};
    #pragma unroll
    for (int p = 0; p < 2; ++p) {
        const unsigned short* W  = p ? Wrb : Wlb;
        const unsigned short* At = p ? sto : agt;
        #pragma unroll
        for (int ks = 0; ks < 4; ++ks) {
            bf16x8 bfr = *(const bf16x8*)&W[(size_t)(wv * 16 + lrow) * D + ks * 32 + lk];
            #pragma unroll
            for (int mt = 0; mt < 4; ++mt) {
                bf16x8 af = *(const bf16x8*)&At[(mt * 16 + lrow) * 136 + ks * 32 + lk];
                acc[mt] = __builtin_amdgcn_mfma_f32_16x16x32_bf16(af, bfr, acc[mt], 0, 0, 0);
            }
        }
    }
    __syncthreads();   // all sto (x-tile) reads done before overwrite
    const int orow = (l >> 4) * 4, ocol = l & 15;
    float bb = bias[wv * 16 + ocol];
    #pragma unroll
    for (int mt = 0; mt < 4; ++mt)
        #pragma unroll
        for (int j = 0; j < 4; ++j)
            sto[(mt * 16 + orow + j) * 136 + wv * 16 + ocol] =
                f2b(fmaxf(acc[mt][j] + bb, 0.0f));
    __syncthreads();
    store_tile(sto, n0, hout);
}

// ------- fused agg + conv2 + U/V: h2 stays in LDS, U/V to global -------
__global__ __launch_bounds__(512) void k_aggconv2uv(const unsigned short* __restrict__ h1b,
                                                    const int* __restrict__ rs,
                                                    const int* __restrict__ re,
                                                    const int* __restrict__ srcs,
                                                    const unsigned short* __restrict__ Wlb,
                                                    const unsigned short* __restrict__ Wrb,
                                                    const float* __restrict__ bias,
                                                    const unsigned short* __restrict__ Wm1b,
                                                    const float* __restrict__ bm1,
                                                    unsigned short* __restrict__ Ub,
                                                    unsigned short* __restrict__ Vb) {
    __shared__ unsigned short agt[64 * 136];
    __shared__ unsigned short sto[64 * 136];
    const int tid = threadIdx.x;
    const int n0 = blockIdx.x * 64;

    stage_tile(h1b, n0, sto);                 // h1 tile -> sto
    gather_mean64(h1b, rs, re, srcs, n0, agt);
    __syncthreads();                          // (a)

    const int wv = tid >> 6, l = tid & 63;
    const int lrow = l & 15, lk = (l >> 4) * 8;
    const int orow = (l >> 4) * 4, ocol = l & 15;

    // phase 1: h2 = relu(agg@W2l^T + b + h1@W2r^T)
    f32x4 acc[4] = {};
    #pragma unroll
    for (int p = 0; p < 2; ++p) {
        const unsigned short* W  = p ? Wrb : Wlb;
        const unsigned short* At = p ? sto : agt;
        #pragma unroll
        for (int ks = 0; ks < 4; ++ks) {
            bf16x8 bfr = *(const bf16x8*)&W[(size_t)(wv * 16 + lrow) * D + ks * 32 + lk];
            #pragma unroll
            for (int mt = 0; mt < 4; ++mt) {
                bf16x8 af = *(const bf16x8*)&At[(mt * 16 + lrow) * 136 + ks * 32 + lk];
                acc[mt] = __builtin_amdgcn_mfma_f32_16x16x32_bf16(af, bfr, acc[mt], 0, 0, 0);
            }
        }
    }
    __syncthreads();                          // (b) all agt/sto reads done
    {   // h2 epilogue -> agt (agt free after (b))
        float bb = bias[wv * 16 + ocol];
        #pragma unroll
        for (int mt = 0; mt < 4; ++mt)
            #pragma unroll
            for (int j = 0; j < 4; ++j)
                agt[(mt * 16 + orow + j) * 136 + wv * 16 + ocol] =
                    f2b(fmaxf(acc[mt][j] + bb, 0.0f));
    }
    __syncthreads();                          // (c) h2 tile complete in agt

    // U/V GEMMs: A = h2 (from agt), B = Wm1 halves
    f32x4 aU[4] = {}, aV[4] = {};
    #pragma unroll
    for (int ks = 0; ks < 4; ++ks) {
        bf16x8 bu = *(const bf16x8*)&Wm1b[(size_t)(wv * 16 + lrow) * 256 + ks * 32 + lk];
        bf16x8 bv = *(const bf16x8*)&Wm1b[(size_t)(wv * 16 + lrow) * 256 + 128 + ks * 32 + lk];
        #pragma unroll
        for (int mt = 0; mt < 4; ++mt) {
            bf16x8 af = *(const bf16x8*)&agt[(mt * 16 + lrow) * 136 + ks * 32 + lk];
            aU[mt] = __builtin_amdgcn_mfma_f32_16x16x32_bf16(af, bu, aU[mt], 0, 0, 0);
            aV[mt] = __builtin_amdgcn_mfma_f32_16x16x32_bf16(af, bv, aV[mt], 0, 0, 0);
        }
    }
    {   // stage U -> sto (h1-tile reads ended at (b))
        float bb = bm1[wv * 16 + ocol];
        #pragma unroll
        for (int mt = 0; mt < 4; ++mt)
            #pragma unroll
            for (int j = 0; j < 4; ++j)
                sto[(mt * 16 + orow + j) * 136 + wv * 16 + ocol] = f2b(aU[mt][j] + bb);
    }
    __syncthreads();                          // (d) U staged; all agt (h2) reads done
    store_tile(sto, n0, Ub);
    {   // stage V -> agt
        #pragma unroll
        for (int mt = 0; mt < 4; ++mt)
            #pragma unroll
            for (int j = 0; j < 4; ++j)
                agt[(mt * 16 + orow + j) * 136 + wv * 16 + ocol] = f2b(aV[mt][j]);
    }
    __syncthreads();                          // (e)
    store_tile(agt, n0, Vb);
}

// ---------------- edge finalize, dst-grouped (round-8 proven), 8-unrolled --
__global__ __launch_bounds__(256) void k_edge2(const unsigned short* __restrict__ Ub,
                                               const unsigned short* __restrict__ Vb,
                                               const int* __restrict__ rs,
                                               const int* __restrict__ re,
                                               const int* __restrict__ srcs,
                                               const int* __restrict__ eids,
                                               const float* __restrict__ wm2,
                                               const float* __restrict__ bm2,
                                               float* __restrict__ out) {
    int t = blockIdx.x * 256 + threadIdx.x;
    int g = t >> 4, q = t & 15;
    if (g >= NN) return;
    int b = rs[g], e = re[g];
    if (b == e) return;
    u16x8 vv = *(const u16x8*)&Vb[(size_t)g * D + q * 8];
    float vf[8], wf[8];
    #pragma unroll
    for (int i = 0; i < 8; ++i) vf[i] = b2f(vv[i]);
    float4 w0 = *(const float4*)&wm2[q * 8];
    float4 w1 = *(const float4*)&wm2[q * 8 + 4];
    wf[0] = w0.x; wf[1] = w0.y; wf[2] = w0.z; wf[3] = w0.w;
    wf[4] = w1.x; wf[5] = w1.y; wf[6] = w1.z; wf[7] = w1.w;
    const float bb = bm2[0];

    int j = b;
    for (; j + 7 < e; j += 8) {
        u16x8 u0 = *(const u16x8*)&Ub[(size_t)srcs[j]     * D + q * 8];
        u16x8 u1 = *(const u16x8*)&Ub[(size_t)srcs[j + 1] * D + q * 8];
        u16x8 u2 = *(const u16x8*)&Ub[(size_t)srcs[j + 2] * D + q * 8];
        u16x8 u3 = *(const u16x8*)&Ub[(size_t)srcs[j + 3] * D + q * 8];
        u16x8 u4 = *(const u16x8*)&Ub[(size_t)srcs[j + 4] * D + q * 8];
        u16x8 u5 = *(const u16x8*)&Ub[(size_t)srcs[j + 5] * D + q * 8];
        u16x8 u6 = *(const u16x8*)&Ub[(size_t)srcs[j + 6] * D + q * 8];
        u16x8 u7 = *(const u16x8*)&Ub[(size_t)srcs[j + 7] * D + q * 8];
        float p0 = 0.f, p1 = 0.f, p2 = 0.f, p3 = 0.f;
        float p4 = 0.f, p5 = 0.f, p6 = 0.f, p7 = 0.f;
        #pragma unroll
        for (int i = 0; i < 8; ++i) {
            p0 += fmaxf(b2f(u0[i]) + vf[i], 0.0f) * wf[i];
            p1 += fmaxf(b2f(u1[i]) + vf[i], 0.0f) * wf[i];
            p2 += fmaxf(b2f(u2[i]) + vf[i], 0.0f) * wf[i];
            p3 += fmaxf(b2f(u3[i]) + vf[i], 0.0f) * wf[i];
            p4 += fmaxf(b2f(u4[i]) + vf[i], 0.0f) * wf[i];
            p5 += fmaxf(b2f(u5[i]) + vf[i], 0.0f) * wf[i];
            p6 += fmaxf(b2f(u6[i]) + vf[i], 0.0f) * wf[i];
            p7 += fmaxf(b2f(u7[i]) + vf[i], 0.0f) * wf[i];
        }
        #pragma unroll
        for (int off = 1; off < 16; off <<= 1) {
            p0 += __shfl_xor(p0, off); p1 += __shfl_xor(p1, off);
            p2 += __shfl_xor(p2, off); p3 += __shfl_xor(p3, off);
            p4 += __shfl_xor(p4, off); p5 += __shfl_xor(p5, off);
            p6 += __shfl_xor(p6, off); p7 += __shfl_xor(p7, off);
        }
        if (q == 0) {
            out[eids[j]]     = 1.0f / (1.0f + expf(-(p0 + bb)));
            out[eids[j + 1]] = 1.0f / (1.0f + expf(-(p1 + bb)));
            out[eids[j + 2]] = 1.0f / (1.0f + expf(-(p2 + bb)));
            out[eids[j + 3]] = 1.0f / (1.0f + expf(-(p3 + bb)));
            out[eids[j + 4]] = 1.0f / (1.0f + expf(-(p4 + bb)));
            out[eids[j + 5]] = 1.0f / (1.0f + expf(-(p5 + bb)));
            out[eids[j + 6]] = 1.0f / (1.0f + expf(-(p6 + bb)));
            out[eids[j + 7]] = 1.0f / (1.0f + expf(-(p7 + bb)));
        }
    }
    for (; j + 3 < e; j += 4) {
        u16x8 u0 = *(const u16x8*)&Ub[(size_t)srcs[j]     * D + q * 8];
        u16x8 u1 = *(const u16x8*)&Ub[(size_t)srcs[j + 1] * D + q * 8];
        u16x8 u2 = *(const u16x8*)&Ub[(size_t)srcs[j + 2] * D + q * 8];
        u16x8 u3 = *(const u16x8*)&Ub[(size_t)srcs[j + 3] * D + q * 8];
        float p0 = 0.f, p1 = 0.f, p2 = 0.f, p3 = 0.f;
        #pragma unroll
        for (int i = 0; i < 8; ++i) {
            p0 += fmaxf(b2f(u0[i]) + vf[i], 0.0f) * wf[i];
            p1 += fmaxf(b2f(u1[i]) + vf[i], 0.0f) * wf[i];
            p2 += fmaxf(b2f(u2[i]) + vf[i], 0.0f) * wf[i];
            p3 += fmaxf(b2f(u3[i]) + vf[i], 0.0f) * wf[i];
        }
        #pragma unroll
        for (int off = 1; off < 16; off <<= 1) {
            p0 += __shfl_xor(p0, off); p1 += __shfl_xor(p1, off);
            p2 += __shfl_xor(p2, off); p3 += __shfl_xor(p3, off);
        }
        if (q == 0) {
            out[eids[j]]     = 1.0f / (1.0f + expf(-(p0 + bb)));
            out[eids[j + 1]] = 1.0f / (1.0f + expf(-(p1 + bb)));
            out[eids[j + 2]] = 1.0f / (1.0f + expf(-(p2 + bb)));
            out[eids[j + 3]] = 1.0f / (1.0f + expf(-(p3 + bb)));
        }
    }
    for (; j < e; ++j) {
        u16x8 u0 = *(const u16x8*)&Ub[(size_t)srcs[j] * D + q * 8];
        float p0 = 0.f;
        #pragma unroll
        for (int i = 0; i < 8; ++i) p0 += fmaxf(b2f(u0[i]) + vf[i], 0.0f) * wf[i];
        #pragma unroll
        for (int off = 1; off < 16; off <<= 1) p0 += __shfl_xor(p0, off);
        if (q == 0) out[eids[j]] = 1.0f / (1.0f + expf(-(p0 + bb)));
    }
}

extern "C" void kernel_launch(void* const* d_in, const int* in_sizes, int n_in,
                              void* d_out, int out_size, void* d_ws, size_t ws_size,
                              hipStream_t stream) {
    const float* x   = (const float*)d_in[0];
    const int*   ei  = (const int*)d_in[1];
    const int*   src = ei;
    const int*   dst = ei + NE;
    const float* W1l = (const float*)d_in[2];
    const float* b1l = (const float*)d_in[3];
    const float* W1r = (const float*)d_in[4];
    const float* W2l = (const float*)d_in[5];
    const float* b2l = (const float*)d_in[6];
    const float* W2r = (const float*)d_in[7];
    const float* Wm1 = (const float*)d_in[8];
    const float* bm1 = (const float*)d_in[9];
    const float* Wm2 = (const float*)d_in[10];
    const float* bm2 = (const float*)d_in[11];
    float* out = (float*)d_out;

    char* ws = (char*)d_ws;
    int* rs   = (int*)(ws + OFF_RS);
    int* cnt  = (int*)(ws + OFF_CNT);
    int* cur  = (int*)(ws + OFF_CUR);    // row_end after scatter_idx
    int* bsum = (int*)(ws + OFF_BS);
    unsigned short* wb = (unsigned short*)(ws + OFF_WB);
    int* srcs = (int*)(ws + OFF_SRC);
    int* eids = (int*)(ws + OFF_EID);
    unsigned short* B0 = (unsigned short*)(ws + OFF_B0);  // xb, later Vb
    unsigned short* B2 = (unsigned short*)(ws + OFF_B2);  // h1b
    unsigned short* B3 = (unsigned short*)(ws + OFF_B3);  // Ub

    unsigned short* W1lb = wb;
    unsigned short* W1rb = wb + 16384;
    unsigned short* W2lb = wb + 32768;
    unsigned short* W2rb = wb + 49152;
    unsigned short* Wm1b = wb + 65536;

    const int NB = 391;   // ceil(NN/256)
    const int NB64 = (NN + 63) / 64;  // 1563

    hipMemsetAsync(cnt, 0, NN * sizeof(int), stream);
    k_prep<<<12500 + 384 + 3125, 256, 0, stream>>>(x, B0, W1l, W1r, W2l, W2r, Wm1,
                                                   wb, dst, cnt);
    k_scan1<<<NB, 256, 0, stream>>>(cnt, bsum);
    k_scan2<<<1, 512, 0, stream>>>(bsum, NB);
    k_scan3<<<NB, 256, 0, stream>>>(cnt, bsum, rs, cur);
    k_scatter_idx<<<(NE + 255) / 256, 256, 0, stream>>>(src, dst, cur, srcs, eids);

    k_aggconv1<<<NB64, 512, 0, stream>>>(B0, rs, cur, srcs, W1lb, W1rb, b1l, B2);   // h1 -> B2
    k_aggconv2uv<<<NB64, 512, 0, stream>>>(B2, rs, cur, srcs, W2lb, W2rb, b2l,
                                           Wm1b, bm1, B3, B0);                      // U -> B3, V -> B0
    k_edge2<<<(NN * 16 + 255) / 256, 256, 0, stream>>>(B3, B0, rs, cur, srcs, eids,
                                                       Wm2, bm2, out);
}

// Round 10
// 283.669 us; speedup vs baseline: 1.1692x; 1.0166x over previous
//
#include <hip/hip_runtime.h>
#include <math.h>

#define NN 100000
#define NE 800000
#define D 128

typedef __attribute__((ext_vector_type(8))) short bf16x8;
typedef __attribute__((ext_vector_type(8))) unsigned short u16x8;
typedef __attribute__((ext_vector_type(4))) float f32x4;
typedef __attribute__((ext_vector_type(2))) float f32x2;

// ---- workspace layout (bytes) ----
constexpr size_t OFF_RS  = 0;                         // int[NN+1]
constexpr size_t OFF_CNT = 512 * 1024;                // int[NN] histogram
constexpr size_t OFF_CUR = 1024 * 1024;               // int[NN] cursor -> row_end
constexpr size_t OFF_BS  = 1536 * 1024;               // int[512] block sums
constexpr size_t OFF_WB  = 1552 * 1024;               // bf16 weights (98304 elems)
constexpr size_t OFF_SRC = 2 * 1024 * 1024;           // int[NE]
constexpr size_t OFF_EID = 6 * 1024 * 1024;           // int[NE]
constexpr size_t OFF_B0  = 10 * 1024 * 1024;          // bf16[100096*128] xb -> Vb
constexpr size_t OFF_B2  = OFF_B0 + 26 * 1024 * 1024; // h1b (bf16, root reads)
constexpr size_t OFF_X8  = OFF_B2 + 26 * 1024 * 1024; // fp8 x   [NN*128]
constexpr size_t OFF_H8  = OFF_X8 + 13 * 1024 * 1024; // fp8 h1  [NN*128]
constexpr size_t OFF_U8  = OFF_H8 + 13 * 1024 * 1024; // fp8 U   [NN*128]

__device__ __forceinline__ unsigned short f2b(float f) {
    unsigned u = __builtin_bit_cast(unsigned, f);
    return (unsigned short)((u + 0x7FFFu + ((u >> 16) & 1u)) >> 16);
}
__device__ __forceinline__ float b2f(unsigned short h) {
    unsigned u = ((unsigned)h) << 16;
    return __builtin_bit_cast(float, u);
}

// ------------- fused prep: x->bf16+fp8 | weights->bf16 | degree histogram ---
__global__ __launch_bounds__(256) void k_prep(const float* __restrict__ x,
                                              unsigned short* __restrict__ xb,
                                              unsigned* __restrict__ x8w,
                                              const float* __restrict__ W1l,
                                              const float* __restrict__ W1r,
                                              const float* __restrict__ W2l,
                                              const float* __restrict__ W2r,
                                              const float* __restrict__ Wm1,
                                              unsigned short* __restrict__ wb,
                                              const int* __restrict__ dst,
                                              int* __restrict__ cnt) {
    int bid = blockIdx.x, tid = threadIdx.x;
    if (bid < 12500) {                       // x conversion, float4 granules
        int i = bid * 256 + tid;             // 3,200,000 = NN*D/4 exactly
        float4 v = *(const float4*)&x[(size_t)i * 4];
        ushort4 o;
        o.x = f2b(v.x); o.y = f2b(v.y); o.z = f2b(v.z); o.w = f2b(v.w);
        *(ushort4*)&xb[(size_t)i * 4] = o;
        unsigned p = __builtin_amdgcn_cvt_pk_fp8_f32(v.x, v.y, 0u, false);
        p = __builtin_amdgcn_cvt_pk_fp8_f32(v.z, v.w, p, true);
        x8w[i] = p;
    } else if (bid < 12884) {                // weights: 98304 elems
        int i = (bid - 12500) * 256 + tid;
        float v;
        if (i < 16384) v = W1l[i];
        else if (i < 32768) v = W1r[i - 16384];
        else if (i < 49152) v = W2l[i - 32768];
        else if (i < 65536) v = W2r[i - 49152];
        else v = Wm1[i - 65536];
        wb[i] = f2b(v);
    } else {                                 // degree histogram
        int e = (bid - 12884) * 256 + tid;
        atomicAdd(&cnt[dst[e]], 1);
    }
}

// ---------------- CSR scan chain ----------------
__global__ __launch_bounds__(256) void k_scan1(const int* __restrict__ cnt,
                                               int* __restrict__ bsum) {
    int i = blockIdx.x * 256 + threadIdx.x;
    int v = (i < NN) ? cnt[i] : 0;
    #pragma unroll
    for (int o = 1; o < 64; o <<= 1) v += __shfl_xor(v, o);
    __shared__ int wsum[4];
    if ((threadIdx.x & 63) == 0) wsum[threadIdx.x >> 6] = v;
    __syncthreads();
    if (threadIdx.x == 0) bsum[blockIdx.x] = wsum[0] + wsum[1] + wsum[2] + wsum[3];
}

__global__ __launch_bounds__(512) void k_scan2(int* __restrict__ bsum, int nb) {
    __shared__ int s[512];
    int t = threadIdx.x;
    int v = (t < nb) ? bsum[t] : 0;
    s[t] = v;
    __syncthreads();
    for (int o = 1; o < 512; o <<= 1) {
        int u = (t >= o) ? s[t - o] : 0;
        __syncthreads();
        s[t] += u;
        __syncthreads();
    }
    if (t < nb) bsum[t] = s[t] - v;   // exclusive
}

__global__ __launch_bounds__(256) void k_scan3(const int* __restrict__ cnt,
                                               const int* __restrict__ bsum,
                                               int* __restrict__ rs,
                                               int* __restrict__ cur) {
    __shared__ int s[256];
    int t = threadIdx.x;
    int i = blockIdx.x * 256 + t;
    int v = (i < NN) ? cnt[i] : 0;
    s[t] = v;
    __syncthreads();
    for (int o = 1; o < 256; o <<= 1) {
        int u = (t >= o) ? s[t - o] : 0;
        __syncthreads();
        s[t] += u;
        __syncthreads();
    }
    int ex = s[t] - v + bsum[blockIdx.x];
    if (i < NN) { rs[i] = ex; cur[i] = ex; }
    if (i == NN - 1) rs[NN] = ex + v;
}

__global__ __launch_bounds__(256) void k_scatter_idx(const int* __restrict__ src,
                                                     const int* __restrict__ dst,
                                                     int* __restrict__ cur,
                                                     int* __restrict__ srcs,
                                                     int* __restrict__ eids) {
    int e = blockIdx.x * 256 + threadIdx.x;
    if (e < NE) {
        int pos = atomicAdd(&cur[dst[e]], 1);
        srcs[pos] = src[e];
        eids[pos] = e;
    }
}

// ---- gather-mean (fp8 rows) for 64 nodes into LDS tile [64][136] bf16 -----
// 16 lanes/node, 8B (8 fp8) per lane per edge, 8-deep unrolled.
#define UNPK8(acc, u) {                                               \
    f32x2 p0 = __builtin_amdgcn_cvt_pk_f32_fp8(u.x, false);           \
    f32x2 p1 = __builtin_amdgcn_cvt_pk_f32_fp8(u.x, true);            \
    f32x2 p2 = __builtin_amdgcn_cvt_pk_f32_fp8(u.y, false);           \
    f32x2 p3 = __builtin_amdgcn_cvt_pk_f32_fp8(u.y, true);            \
    acc[0] += p0.x; acc[1] += p0.y; acc[2] += p1.x; acc[3] += p1.y;   \
    acc[4] += p2.x; acc[5] += p2.y; acc[6] += p3.x; acc[7] += p3.y; }

__device__ __forceinline__ void gather_mean64(const unsigned char* __restrict__ feat8,
                                              const int* __restrict__ rs,
                                              const int* __restrict__ re,
                                              const int* __restrict__ srcs,
                                              int n0, unsigned short* agt) {
    const int tid = threadIdx.x;
    const int g = tid >> 4, q = tid & 15;   // g in 0..31
    #pragma unroll
    for (int half = 0; half < 2; ++half) {
        int r = half * 32 + g;
        int n = n0 + r;
        if (n > NN - 1) n = NN - 1;          // tail clamp (NN%64==32)
        int b = rs[n], e = re[n];
        float a0[8] = {}, a1[8] = {}, a2[8] = {}, a3[8] = {};
        int j = b;
        for (; j + 7 < e; j += 8) {
            uint2 v0 = *(const uint2*)&feat8[(size_t)srcs[j]     * 128 + q * 8];
            uint2 v1 = *(const uint2*)&feat8[(size_t)srcs[j + 1] * 128 + q * 8];
            uint2 v2 = *(const uint2*)&feat8[(size_t)srcs[j + 2] * 128 + q * 8];
            uint2 v3 = *(const uint2*)&feat8[(size_t)srcs[j + 3] * 128 + q * 8];
            uint2 v4 = *(const uint2*)&feat8[(size_t)srcs[j + 4] * 128 + q * 8];
            uint2 v5 = *(const uint2*)&feat8[(size_t)srcs[j + 5] * 128 + q * 8];
            uint2 v6 = *(const uint2*)&feat8[(size_t)srcs[j + 6] * 128 + q * 8];
            uint2 v7 = *(const uint2*)&feat8[(size_t)srcs[j + 7] * 128 + q * 8];
            UNPK8(a0, v0); UNPK8(a1, v1); UNPK8(a2, v2); UNPK8(a3, v3);
            UNPK8(a0, v4); UNPK8(a1, v5); UNPK8(a2, v6); UNPK8(a3, v7);
        }
        for (; j + 3 < e; j += 4) {
            uint2 v0 = *(const uint2*)&feat8[(size_t)srcs[j]     * 128 + q * 8];
            uint2 v1 = *(const uint2*)&feat8[(size_t)srcs[j + 1] * 128 + q * 8];
            uint2 v2 = *(const uint2*)&feat8[(size_t)srcs[j + 2] * 128 + q * 8];
            uint2 v3 = *(const uint2*)&feat8[(size_t)srcs[j + 3] * 128 + q * 8];
            UNPK8(a0, v0); UNPK8(a1, v1); UNPK8(a2, v2); UNPK8(a3, v3);
        }
        for (; j < e; ++j) {
            uint2 v0 = *(const uint2*)&feat8[(size_t)srcs[j] * 128 + q * 8];
            UNPK8(a0, v0);
        }
        float inv = 1.0f / fmaxf((float)(e - b), 1.0f);
        u16x8 o;
        #pragma unroll
        for (int i = 0; i < 8; ++i) o[i] = f2b((a0[i] + a1[i] + a2[i] + a3[i]) * inv);
        *(u16x8*)&agt[r * 136 + q * 8] = o;
    }
}

// stage 64 global bf16 rows -> LDS tile [64][136] (coalesced, clamped)
__device__ __forceinline__ void stage_tile(const unsigned short* __restrict__ src,
                                           int n0, unsigned short* t) {
    const int tid = threadIdx.x;
    #pragma unroll
    for (int it = 0; it < 2; ++it) {
        int idx = it * 512 + tid;
        int r = idx >> 4, c = (idx & 15) * 8;
        int gr = n0 + r;
        if (gr > NN - 1) gr = NN - 1;
        *(u16x8*)&t[r * 136 + c] = *(const u16x8*)&src[(size_t)gr * D + c];
    }
}

// store LDS tile [64][136] -> global bf16 (coalesced, guarded)
__device__ __forceinline__ void store_tile(const unsigned short* t,
                                           int n0, unsigned short* __restrict__ dstp) {
    const int tid = threadIdx.x;
    #pragma unroll
    for (int it = 0; it < 2; ++it) {
        int idx = it * 512 + tid;
        int r = idx >> 4, c = (idx & 15) * 8;
        int gr = n0 + r;
        if (gr < NN)
            *(u16x8*)&dstp[(size_t)gr * D + c] = *(const u16x8*)&t[r * 136 + c];
    }
}

// store LDS bf16 tile -> global fp8 (coalesced 4B words, guarded)
__device__ __forceinline__ void store_tile_fp8(const unsigned short* t,
                                               int n0, unsigned char* __restrict__ dst8) {
    const int tid = threadIdx.x;
    #pragma unroll
    for (int it = 0; it < 4; ++it) {
        int w = it * 512 + tid;          // word 0..2047
        int r = w >> 5, c4 = (w & 31) * 4;
        int gr = n0 + r;
        if (gr < NN) {
            unsigned p = __builtin_amdgcn_cvt_pk_fp8_f32(
                b2f(t[r * 136 + c4 + 0]), b2f(t[r * 136 + c4 + 1]), 0u, false);
            p = __builtin_amdgcn_cvt_pk_fp8_f32(
                b2f(t[r * 136 + c4 + 2]), b2f(t[r * 136 + c4 + 3]), p, true);
            *(unsigned*)&dst8[(size_t)gr * 128 + c4] = p;
        }
    }
}

// ---------------- fused agg + conv1: h1 = relu(mean@W1l^T + b + x@W1r^T) ----
__global__ __launch_bounds__(512) void k_aggconv1(const unsigned short* __restrict__ xb,
                                                  const unsigned char* __restrict__ x8,
                                                  const int* __restrict__ rs,
                                                  const int* __restrict__ re,
                                                  const int* __restrict__ srcs,
                                                  const unsigned short* __restrict__ Wlb,
                                                  const unsigned short* __restrict__ Wrb,
                                                  const float* __restrict__ bias,
                                                  unsigned short* __restrict__ hout,
                                                  unsigned char* __restrict__ h8) {
    __shared__ unsigned short agt[64 * 136];
    __shared__ unsigned short sto[64 * 136];
    const int tid = threadIdx.x;
    const int n0 = blockIdx.x * 64;

    stage_tile(xb, n0, sto);
    gather_mean64(x8, rs, re, srcs, n0, agt);
    __syncthreads();

    const int wv = tid >> 6, l = tid & 63;
    const int lrow = l & 15, lk = (l >> 4) * 8;
    f32x4 acc[4] = {};
    #pragma unroll
    for (int p = 0; p < 2; ++p) {
        const unsigned short* W  = p ? Wrb : Wlb;
        const unsigned short* At = p ? sto : agt;
        #pragma unroll
        for (int ks = 0; ks < 4; ++ks) {
            bf16x8 bfr = *(const bf16x8*)&W[(size_t)(wv * 16 + lrow) * D + ks * 32 + lk];
            #pragma unroll
            for (int mt = 0; mt < 4; ++mt) {
                bf16x8 af = *(const bf16x8*)&At[(mt * 16 + lrow) * 136 + ks * 32 + lk];
                acc[mt] = __builtin_amdgcn_mfma_f32_16x16x32_bf16(af, bfr, acc[mt], 0, 0, 0);
            }
        }
    }
    __syncthreads();   // all sto (x-tile) reads done before overwrite
    const int orow = (l >> 4) * 4, ocol = l & 15;
    float bb = bias[wv * 16 + ocol];
    #pragma unroll
    for (int mt = 0; mt < 4; ++mt)
        #pragma unroll
        for (int j = 0; j < 4; ++j)
            sto[(mt * 16 + orow + j) * 136 + wv * 16 + ocol] =
                f2b(fmaxf(acc[mt][j] + bb, 0.0f));
    __syncthreads();
    store_tile(sto, n0, hout);
    store_tile_fp8(sto, n0, h8);
}

// ------- fused agg + conv2 + U/V: h2 in LDS; U -> fp8, V -> bf16 -------
__global__ __launch_bounds__(512) void k_aggconv2uv(const unsigned short* __restrict__ h1b,
                                                    const unsigned char* __restrict__ h8,
                                                    const int* __restrict__ rs,
                                                    const int* __restrict__ re,
                                                    const int* __restrict__ srcs,
                                                    const unsigned short* __restrict__ Wlb,
                                                    const unsigned short* __restrict__ Wrb,
                                                    const float* __restrict__ bias,
                                                    const unsigned short* __restrict__ Wm1b,
                                                    const float* __restrict__ bm1,
                                                    unsigned char* __restrict__ U8,
                                                    unsigned short* __restrict__ Vb) {
    __shared__ unsigned short agt[64 * 136];
    __shared__ unsigned short sto[64 * 136];
    const int tid = threadIdx.x;
    const int n0 = blockIdx.x * 64;

    stage_tile(h1b, n0, sto);                 // h1 tile (root) -> sto
    gather_mean64(h8, rs, re, srcs, n0, agt); // fp8 gather
    __syncthreads();                          // (a)

    const int wv = tid >> 6, l = tid & 63;
    const int lrow = l & 15, lk = (l >> 4) * 8;
    const int orow = (l >> 4) * 4, ocol = l & 15;

    // phase 1: h2 = relu(agg@W2l^T + b + h1@W2r^T)
    f32x4 acc[4] = {};
    #pragma unroll
    for (int p = 0; p < 2; ++p) {
        const unsigned short* W  = p ? Wrb : Wlb;
        const unsigned short* At = p ? sto : agt;
        #pragma unroll
        for (int ks = 0; ks < 4; ++ks) {
            bf16x8 bfr = *(const bf16x8*)&W[(size_t)(wv * 16 + lrow) * D + ks * 32 + lk];
            #pragma unroll
            for (int mt = 0; mt < 4; ++mt) {
                bf16x8 af = *(const bf16x8*)&At[(mt * 16 + lrow) * 136 + ks * 32 + lk];
                acc[mt] = __builtin_amdgcn_mfma_f32_16x16x32_bf16(af, bfr, acc[mt], 0, 0, 0);
            }
        }
    }
    __syncthreads();                          // (b) all agt/sto reads done
    {   // h2 epilogue -> agt
        float bb = bias[wv * 16 + ocol];
        #pragma unroll
        for (int mt = 0; mt < 4; ++mt)
            #pragma unroll
            for (int j = 0; j < 4; ++j)
                agt[(mt * 16 + orow + j) * 136 + wv * 16 + ocol] =
                    f2b(fmaxf(acc[mt][j] + bb, 0.0f));
    }
    __syncthreads();                          // (c) h2 tile complete in agt

    f32x4 aU[4] = {}, aV[4] = {};
    #pragma unroll
    for (int ks = 0; ks < 4; ++ks) {
        bf16x8 bu = *(const bf16x8*)&Wm1b[(size_t)(wv * 16 + lrow) * 256 + ks * 32 + lk];
        bf16x8 bv = *(const bf16x8*)&Wm1b[(size_t)(wv * 16 + lrow) * 256 + 128 + ks * 32 + lk];
        #pragma unroll
        for (int mt = 0; mt < 4; ++mt) {
            bf16x8 af = *(const bf16x8*)&agt[(mt * 16 + lrow) * 136 + ks * 32 + lk];
            aU[mt] = __builtin_amdgcn_mfma_f32_16x16x32_bf16(af, bu, aU[mt], 0, 0, 0);
            aV[mt] = __builtin_amdgcn_mfma_f32_16x16x32_bf16(af, bv, aV[mt], 0, 0, 0);
        }
    }
    {   // stage U -> sto (h1-tile reads ended at (b))
        float bb = bm1[wv * 16 + ocol];
        #pragma unroll
        for (int mt = 0; mt < 4; ++mt)
            #pragma unroll
            for (int j = 0; j < 4; ++j)
                sto[(mt * 16 + orow + j) * 136 + wv * 16 + ocol] = f2b(aU[mt][j] + bb);
    }
    __syncthreads();                          // (d) U staged; all agt (h2) reads done
    store_tile_fp8(sto, n0, U8);              // U only as fp8
    {   // stage V -> agt
        #pragma unroll
        for (int mt = 0; mt < 4; ++mt)
            #pragma unroll
            for (int j = 0; j < 4; ++j)
                agt[(mt * 16 + orow + j) * 136 + wv * 16 + ocol] = f2b(aV[mt][j]);
    }
    __syncthreads();                          // (e)
    store_tile(agt, n0, Vb);
}

// ---------------- edge finalize, dst-grouped, U gathered as fp8 ------------
__global__ __launch_bounds__(256) void k_edge2(const unsigned char* __restrict__ U8,
                                               const unsigned short* __restrict__ Vb,
                                               const int* __restrict__ rs,
                                               const int* __restrict__ re,
                                               const int* __restrict__ srcs,
                                               const int* __restrict__ eids,
                                               const float* __restrict__ wm2,
                                               const float* __restrict__ bm2,
                                               float* __restrict__ out) {
    int t = blockIdx.x * 256 + threadIdx.x;
    int g = t >> 4, q = t & 15;
    if (g >= NN) return;
    int b = rs[g], e = re[g];
    if (b == e) return;
    u16x8 vv = *(const u16x8*)&Vb[(size_t)g * D + q * 8];
    float vf[8], wf[8];
    #pragma unroll
    for (int i = 0; i < 8; ++i) vf[i] = b2f(vv[i]);
    float4 w0 = *(const float4*)&wm2[q * 8];
    float4 w1 = *(const float4*)&wm2[q * 8 + 4];
    wf[0] = w0.x; wf[1] = w0.y; wf[2] = w0.z; wf[3] = w0.w;
    wf[4] = w1.x; wf[5] = w1.y; wf[6] = w1.z; wf[7] = w1.w;
    const float bb = bm2[0];

#define EDOT(p, u) {                                                   \
    f32x2 q0 = __builtin_amdgcn_cvt_pk_f32_fp8(u.x, false);            \
    f32x2 q1 = __builtin_amdgcn_cvt_pk_f32_fp8(u.x, true);             \
    f32x2 q2 = __builtin_amdgcn_cvt_pk_f32_fp8(u.y, false);            \
    f32x2 q3 = __builtin_amdgcn_cvt_pk_f32_fp8(u.y, true);             \
    p += fmaxf(q0.x + vf[0], 0.0f) * wf[0] + fmaxf(q0.y + vf[1], 0.0f) * wf[1] \
       + fmaxf(q1.x + vf[2], 0.0f) * wf[2] + fmaxf(q1.y + vf[3], 0.0f) * wf[3] \
       + fmaxf(q2.x + vf[4], 0.0f) * wf[4] + fmaxf(q2.y + vf[5], 0.0f) * wf[5] \
       + fmaxf(q3.x + vf[6], 0.0f) * wf[6] + fmaxf(q3.y + vf[7], 0.0f) * wf[7]; }

    int j = b;
    for (; j + 7 < e; j += 8) {
        uint2 u0 = *(const uint2*)&U8[(size_t)srcs[j]     * 128 + q * 8];
        uint2 u1 = *(const uint2*)&U8[(size_t)srcs[j + 1] * 128 + q * 8];
        uint2 u2 = *(const uint2*)&U8[(size_t)srcs[j + 2] * 128 + q * 8];
        uint2 u3 = *(const uint2*)&U8[(size_t)srcs[j + 3] * 128 + q * 8];
        uint2 u4 = *(const uint2*)&U8[(size_t)srcs[j + 4] * 128 + q * 8];
        uint2 u5 = *(const uint2*)&U8[(size_t)srcs[j + 5] * 128 + q * 8];
        uint2 u6 = *(const uint2*)&U8[(size_t)srcs[j + 6] * 128 + q * 8];
        uint2 u7 = *(const uint2*)&U8[(size_t)srcs[j + 7] * 128 + q * 8];
        float p0 = 0.f, p1 = 0.f, p2 = 0.f, p3 = 0.f;
        float p4 = 0.f, p5 = 0.f, p6 = 0.f, p7 = 0.f;
        EDOT(p0, u0); EDOT(p1, u1); EDOT(p2, u2); EDOT(p3, u3);
        EDOT(p4, u4); EDOT(p5, u5); EDOT(p6, u6); EDOT(p7, u7);
        #pragma unroll
        for (int off = 1; off < 16; off <<= 1) {
            p0 += __shfl_xor(p0, off); p1 += __shfl_xor(p1, off);
            p2 += __shfl_xor(p2, off); p3 += __shfl_xor(p3, off);
            p4 += __shfl_xor(p4, off); p5 += __shfl_xor(p5, off);
            p6 += __shfl_xor(p6, off); p7 += __shfl_xor(p7, off);
        }
        if (q == 0) {
            out[eids[j]]     = 1.0f / (1.0f + expf(-(p0 + bb)));
            out[eids[j + 1]] = 1.0f / (1.0f + expf(-(p1 + bb)));
            out[eids[j + 2]] = 1.0f / (1.0f + expf(-(p2 + bb)));
            out[eids[j + 3]] = 1.0f / (1.0f + expf(-(p3 + bb)));
            out[eids[j + 4]] = 1.0f / (1.0f + expf(-(p4 + bb)));
            out[eids[j + 5]] = 1.0f / (1.0f + expf(-(p5 + bb)));
            out[eids[j + 6]] = 1.0f / (1.0f + expf(-(p6 + bb)));
            out[eids[j + 7]] = 1.0f / (1.0f + expf(-(p7 + bb)));
        }
    }
    for (; j + 3 < e; j += 4) {
        uint2 u0 = *(const uint2*)&U8[(size_t)srcs[j]     * 128 + q * 8];
        uint2 u1 = *(const uint2*)&U8[(size_t)srcs[j + 1] * 128 + q * 8];
        uint2 u2 = *(const uint2*)&U8[(size_t)srcs[j + 2] * 128 + q * 8];
        uint2 u3 = *(const uint2*)&U8[(size_t)srcs[j + 3] * 128 + q * 8];
        float p0 = 0.f, p1 = 0.f, p2 = 0.f, p3 = 0.f;
        EDOT(p0, u0); EDOT(p1, u1); EDOT(p2, u2); EDOT(p3, u3);
        #pragma unroll
        for (int off = 1; off < 16; off <<= 1) {
            p0 += __shfl_xor(p0, off); p1 += __shfl_xor(p1, off);
            p2 += __shfl_xor(p2, off); p3 += __shfl_xor(p3, off);
        }
        if (q == 0) {
            out[eids[j]]     = 1.0f / (1.0f + expf(-(p0 + bb)));
            out[eids[j + 1]] = 1.0f / (1.0f + expf(-(p1 + bb)));
            out[eids[j + 2]] = 1.0f / (1.0f + expf(-(p2 + bb)));
            out[eids[j + 3]] = 1.0f / (1.0f + expf(-(p3 + bb)));
        }
    }
    for (; j < e; ++j) {
        uint2 u0 = *(const uint2*)&U8[(size_t)srcs[j] * 128 + q * 8];
        float p0 = 0.f;
        EDOT(p0, u0);
        #pragma unroll
        for (int off = 1; off < 16; off <<= 1) p0 += __shfl_xor(p0, off);
        if (q == 0) out[eids[j]] = 1.0f / (1.0f + expf(-(p0 + bb)));
    }
}

extern "C" void kernel_launch(void* const* d_in, const int* in_sizes, int n_in,
                              void* d_out, int out_size, void* d_ws, size_t ws_size,
                              hipStream_t stream) {
    const float* x   = (const float*)d_in[0];
    const int*   ei  = (const int*)d_in[1];
    const int*   src = ei;
    const int*   dst = ei + NE;
    const float* W1l = (const float*)d_in[2];
    const float* b1l = (const float*)d_in[3];
    const float* W1r = (const float*)d_in[4];
    const float* W2l = (const float*)d_in[5];
    const float* b2l = (const float*)d_in[6];
    const float* W2r = (const float*)d_in[7];
    const float* Wm1 = (const float*)d_in[8];
    const float* bm1 = (const float*)d_in[9];
    const float* Wm2 = (const float*)d_in[10];
    const float* bm2 = (const float*)d_in[11];
    float* out = (float*)d_out;

    char* ws = (char*)d_ws;
    int* rs   = (int*)(ws + OFF_RS);
    int* cnt  = (int*)(ws + OFF_CNT);
    int* cur  = (int*)(ws + OFF_CUR);    // row_end after scatter_idx
    int* bsum = (int*)(ws + OFF_BS);
    unsigned short* wb = (unsigned short*)(ws + OFF_WB);
    int* srcs = (int*)(ws + OFF_SRC);
    int* eids = (int*)(ws + OFF_EID);
    unsigned short* B0 = (unsigned short*)(ws + OFF_B0);  // xb, later Vb
    unsigned short* B2 = (unsigned short*)(ws + OFF_B2);  // h1b (root reads)
    unsigned char*  X8 = (unsigned char*)(ws + OFF_X8);   // fp8 x
    unsigned char*  H8 = (unsigned char*)(ws + OFF_H8);   // fp8 h1
    unsigned char*  U8 = (unsigned char*)(ws + OFF_U8);   // fp8 U

    unsigned short* W1lb = wb;
    unsigned short* W1rb = wb + 16384;
    unsigned short* W2lb = wb + 32768;
    unsigned short* W2rb = wb + 49152;
    unsigned short* Wm1b = wb + 65536;

    const int NB = 391;               // ceil(NN/256)
    const int NB64 = (NN + 63) / 64;  // 1563

    hipMemsetAsync(cnt, 0, NN * sizeof(int), stream);
    k_prep<<<12500 + 384 + 3125, 256, 0, stream>>>(x, B0, (unsigned*)X8,
                                                   W1l, W1r, W2l, W2r, Wm1,
                                                   wb, dst, cnt);
    k_scan1<<<NB, 256, 0, stream>>>(cnt, bsum);
    k_scan2<<<1, 512, 0, stream>>>(bsum, NB);
    k_scan3<<<NB, 256, 0, stream>>>(cnt, bsum, rs, cur);
    k_scatter_idx<<<(NE + 255) / 256, 256, 0, stream>>>(src, dst, cur, srcs, eids);

    k_aggconv1<<<NB64, 512, 0, stream>>>(B0, X8, rs, cur, srcs,
                                         W1lb, W1rb, b1l, B2, H8);         // h1 -> B2 + H8
    k_aggconv2uv<<<NB64, 512, 0, stream>>>(B2, H8, rs, cur, srcs,
                                           W2lb, W2rb, b2l, Wm1b, bm1,
                                           U8, B0);                        // U -> U8, V -> B0
    k_edge2<<<(NN * 16 + 255) / 256, 256, 0, stream>>>(U8, B0, rs, cur, srcs, eids,
                                                       Wm2, bm2, out);
}